// Round 1
// baseline (717.421 us; speedup 1.0000x reference)
//
#include <hip/hip_runtime.h>
#include <hip/hip_bf16.h>
#include <cstdint>
#include <cstddef>

#define NB 2
#define NSEQ 2048
#define NHEADS 16
#define HD 64
#define DMODEL 1024
#define SCALEF 0.125f

typedef __attribute__((ext_vector_type(4))) float f32x4;
typedef __attribute__((ext_vector_type(8))) short s16x8;

__device__ __forceinline__ unsigned short f2bf(float f) {
  union { float f; unsigned u; } v; v.f = f;
  unsigned u = v.u;
  return (unsigned short)((u + 0x7fffu + ((u >> 16) & 1u)) >> 16);
}

// ---------- fp32 -> bf16 straight convert (float4 vectorized) ----------
__global__ void k_convert(const float* __restrict__ in, unsigned short* __restrict__ out, int n4) {
  int i = blockIdx.x * blockDim.x + threadIdx.x;
  if (i >= n4) return;
  float4 v = ((const float4*)in)[i];
  ushort4 o;
  o.x = f2bf(v.x); o.y = f2bf(v.y); o.z = f2bf(v.z); o.w = f2bf(v.w);
  ((ushort4*)out)[i] = o;
}

// ---------- w [K][N] fp32 -> wt [N][K] bf16 (LDS-tiled transpose) ----------
__global__ void k_transpose(const float* __restrict__ w, unsigned short* __restrict__ wt, int K, int N) {
  __shared__ float t[64][65];
  int n0 = blockIdx.x * 64, k0 = blockIdx.y * 64;
  int c = threadIdx.x & 63, rb = threadIdx.x >> 6;
#pragma unroll
  for (int rr = 0; rr < 16; rr++) {
    int k = rb * 16 + rr;
    t[c][k] = w[(size_t)(k0 + k) * N + n0 + c];   // store transposed: t[n][k]
  }
  __syncthreads();
#pragma unroll
  for (int rr = 0; rr < 16; rr++) {
    int n = rb * 16 + rr;
    wt[(size_t)(n0 + n) * K + k0 + c] = f2bf(t[n][c]);
  }
}

// ---------- bf16 MFMA GEMM: C[M][N] = A[M][K] @ Bt[N][K]^T (+bias) ----------
#define GLD16(gp, lp) __builtin_amdgcn_global_load_lds( \
    (const __attribute__((address_space(1))) unsigned int*)(gp), \
    (__attribute__((address_space(3))) unsigned int*)(lp), 16, 0, 0)

__global__ __launch_bounds__(256) void k_gemm(const unsigned short* __restrict__ A,
                                              const unsigned short* __restrict__ Bt,
                                              float* __restrict__ C,
                                              const float* __restrict__ bias,
                                              int M, int N, int K) {
  __shared__ unsigned short As[128 * 32];
  __shared__ unsigned short Bs[128 * 32];
  const int tid = threadIdx.x;
  const int lane = tid & 63, wid = tid >> 6;
  const int m0 = blockIdx.y * 128, n0 = blockIdx.x * 128;
  const int wr = wid >> 1, wc = wid & 1;
  const int lr = lane >> 2, l4 = lane & 3;
  const int lc = lane & 15, lg = lane >> 4;

  const unsigned short* pa0 = A + (size_t)(m0 + wid * 32 + lr) * K + l4 * 8;
  const unsigned short* pa1 = pa0 + (size_t)16 * K;
  const unsigned short* pb0 = Bt + (size_t)(n0 + wid * 32 + lr) * K + l4 * 8;
  const unsigned short* pb1 = pb0 + (size_t)16 * K;

  f32x4 acc[4][4] = {};

  for (int kt = 0; kt < K; kt += 32) {
    GLD16(pa0 + kt, &As[wid * 1024]);
    GLD16(pa1 + kt, &As[wid * 1024 + 512]);
    GLD16(pb0 + kt, &Bs[wid * 1024]);
    GLD16(pb1 + kt, &Bs[wid * 1024 + 512]);
    __syncthreads();
    s16x8 af[4], bfr[4];
#pragma unroll
    for (int m = 0; m < 4; m++)
      af[m] = *(const s16x8*)&As[(wr * 64 + m * 16 + lc) * 32 + lg * 8];
#pragma unroll
    for (int n = 0; n < 4; n++)
      bfr[n] = *(const s16x8*)&Bs[(wc * 64 + n * 16 + lc) * 32 + lg * 8];
#pragma unroll
    for (int m = 0; m < 4; m++)
#pragma unroll
      for (int n = 0; n < 4; n++)
        acc[m][n] = __builtin_amdgcn_mfma_f32_16x16x32_bf16(af[m], bfr[n], acc[m][n], 0, 0, 0);
    __syncthreads();
  }

  float bv[4] = {0.f, 0.f, 0.f, 0.f};
  if (bias) {
#pragma unroll
    for (int n = 0; n < 4; n++) bv[n] = bias[n0 + wc * 64 + n * 16 + lc];
  }
#pragma unroll
  for (int m = 0; m < 4; m++) {
#pragma unroll
    for (int n = 0; n < 4; n++) {
      int col = n0 + wc * 64 + n * 16 + lc;
#pragma unroll
      for (int r = 0; r < 4; r++) {
        int row = m0 + wr * 64 + m * 16 + lg * 4 + r;
        C[(size_t)row * N + col] = acc[m][n][r] + bv[n];
      }
    }
  }
}

// ---------- RoPE + head-split relayout: [B][N][H*64] f32 -> [B][H][N][64] bf16 ----------
__global__ void k_rope(const float* __restrict__ src, int row_stride,
                       const float* __restrict__ sinp, const float* __restrict__ cosp,
                       unsigned short* __restrict__ dst) {
  int tid = blockIdx.x * 256 + threadIdx.x;   // B*2048*16*32 threads, 1 pair each
  int p = tid & 31;
  int h = (tid >> 5) & 15;
  int i = (tid >> 9) & 2047;
  int b = tid >> 20;
  int d = p * 2;
  float2 x = *(const float2*)(src + (size_t)(b * NSEQ + i) * row_stride + h * HD + d);
  float o0, o1;
  if (p < 16) {
    size_t sc = (size_t)(b * NSEQ + i) * 32 + d;
    float2 cc = *(const float2*)(cosp + sc);
    float2 ss = *(const float2*)(sinp + sc);
    o0 = x.x * cc.x - x.y * ss.x;   // out[2m] = x0*c0 - x1*s0
    o1 = x.y * cc.y + x.x * ss.y;   // out[2m+1] = x1*c1 + x0*s1
  } else { o0 = x.x; o1 = x.y; }
  size_t off = ((size_t)(b * NHEADS + h) * NSEQ + i) * HD + d;
  unsigned pack = (unsigned)f2bf(o0) | ((unsigned)f2bf(o1) << 16);
  *(unsigned*)(dst + off) = pack;
}

// ---------- v relayout+transpose: kv[B][N][2048](cols 1024..) -> vt [B][H][64][N] bf16 ----------
__global__ void k_vtrans(const float* __restrict__ kv, unsigned short* __restrict__ vt) {
  __shared__ float t[64][65];
  int i0 = blockIdx.x * 64;
  int h = blockIdx.y, b = blockIdx.z;
  int c = threadIdx.x & 63, rb = threadIdx.x >> 6;
#pragma unroll
  for (int rr = 0; rr < 16; rr++) {
    int il = rb * 16 + rr;
    t[il][c] = kv[(size_t)(b * NSEQ + i0 + il) * 2048 + 1024 + h * HD + c];
  }
  __syncthreads();
#pragma unroll
  for (int rr = 0; rr < 16; rr++) {
    int dd = rb * 16 + rr;
    vt[((size_t)(b * NHEADS + h) * HD + dd) * NSEQ + i0 + c] = f2bf(t[c][dd]);
  }
}

// ---------- fused attention: QK^T -> softmax -> write attn -> PV ----------
// block: 256 thr (4 waves), 16 q-rows. S tile [16][2052] fp32 in LDS.
__global__ __launch_bounds__(256) void k_attn(const unsigned short* __restrict__ qh,
                                              const unsigned short* __restrict__ kh,
                                              const unsigned short* __restrict__ vt,
                                              float* __restrict__ attn_g,
                                              unsigned short* __restrict__ ctx) {
  const int SROW = NSEQ + 4;                 // +4 floats: spreads 16B bank-slots
  __shared__ float S[16 * (NSEQ + 4)];       // 131,328 B
  __shared__ float part[4 * 16 * 64];        // 16,384 B
  __shared__ float invr[16];

  const int tid = threadIdx.x;
  const int lane = tid & 63, wid = tid >> 6;
  const int i0 = blockIdx.x * 16;
  const int h = blockIdx.y, b = blockIdx.z;
  const int lc = lane & 15, lg = lane >> 4;

  const unsigned short* qb = qh + ((size_t)(b * NHEADS + h) * NSEQ + i0) * HD;
  const unsigned short* kb = kh + (size_t)(b * NHEADS + h) * NSEQ * HD;
  const unsigned short* vb = vt + (size_t)(b * NHEADS + h) * HD * NSEQ;

  // ---- QK^T: each wave covers j in [wid*512, wid*512+512) ----
  s16x8 aq0 = *(const s16x8*)&qb[lc * HD + lg * 8];
  s16x8 aq1 = *(const s16x8*)&qb[lc * HD + 32 + lg * 8];
#pragma unroll 4
  for (int jf = 0; jf < 32; jf++) {
    int j = wid * 512 + jf * 16;
    f32x4 acc = {};
    s16x8 bk0 = *(const s16x8*)&kb[(size_t)(j + lc) * HD + lg * 8];
    s16x8 bk1 = *(const s16x8*)&kb[(size_t)(j + lc) * HD + 32 + lg * 8];
    acc = __builtin_amdgcn_mfma_f32_16x16x32_bf16(aq0, bk0, acc, 0, 0, 0);
    acc = __builtin_amdgcn_mfma_f32_16x16x32_bf16(aq1, bk1, acc, 0, 0, 0);
#pragma unroll
    for (int r = 0; r < 4; r++)
      S[(size_t)(lg * 4 + r) * SROW + j + lc] = acc[r] * SCALEF;
  }
  __syncthreads();

  // ---- softmax: thread -> (row = tid>>4), scans cols 4*(tid&15) + 64m ----
  const int row = tid >> 4;
  const int c0 = (tid & 15) * 4;
  float* Srow = S + (size_t)row * SROW;

  float mx = -1e30f;
#pragma unroll 8
  for (int m = 0; m < 32; m++) {
    float4 v = *(float4*)&Srow[c0 + m * 64];
    mx = fmaxf(mx, fmaxf(fmaxf(v.x, v.y), fmaxf(v.z, v.w)));
  }
#pragma unroll
  for (int off = 8; off >= 1; off >>= 1) mx = fmaxf(mx, __shfl_xor(mx, off));

  float sum = 0.f;
#pragma unroll 8
  for (int m = 0; m < 32; m++) {
    float4 v = *(float4*)&Srow[c0 + m * 64];
    v.x = __expf(v.x - mx); v.y = __expf(v.y - mx);
    v.z = __expf(v.z - mx); v.w = __expf(v.w - mx);
    *(float4*)&Srow[c0 + m * 64] = v;   // S now holds unnormalized exp
    sum += v.x + v.y + v.z + v.w;
  }
#pragma unroll
  for (int off = 8; off >= 1; off >>= 1) sum += __shfl_xor(sum, off);
  float inv = 1.0f / sum;
  if ((tid & 15) == 0) invr[row] = inv;

  float* arow = attn_g + ((size_t)(b * NHEADS + h) * NSEQ + i0 + row) * NSEQ;
#pragma unroll 8
  for (int m = 0; m < 32; m++) {
    float4 v = *(float4*)&Srow[c0 + m * 64];
    v.x *= inv; v.y *= inv; v.z *= inv; v.w *= inv;
    *(float4*)&arow[c0 + m * 64] = v;   // normalized attn -> global only
  }
  __syncthreads();

  // ---- PV: out[16][64] += exp(S) @ v ; per wave over its j-range ----
  f32x4 accd[4] = {};
  for (int jj = 0; jj < 16; jj++) {
    int jb = wid * 512 + jj * 32;
    float4 a0 = *(float4*)&S[(size_t)lc * SROW + jb + lg * 8];
    float4 a1 = *(float4*)&S[(size_t)lc * SROW + jb + lg * 8 + 4];
    s16x8 af;
    af[0] = (short)f2bf(a0.x); af[1] = (short)f2bf(a0.y);
    af[2] = (short)f2bf(a0.z); af[3] = (short)f2bf(a0.w);
    af[4] = (short)f2bf(a1.x); af[5] = (short)f2bf(a1.y);
    af[6] = (short)f2bf(a1.z); af[7] = (short)f2bf(a1.w);
#pragma unroll
    for (int f = 0; f < 4; f++) {
      s16x8 bv = *(const s16x8*)&vb[(size_t)(f * 16 + lc) * NSEQ + jb + lg * 8];
      accd[f] = __builtin_amdgcn_mfma_f32_16x16x32_bf16(af, bv, accd[f], 0, 0, 0);
    }
  }
#pragma unroll
  for (int f = 0; f < 4; f++)
#pragma unroll
    for (int r = 0; r < 4; r++)
      part[(size_t)(wid * 16 + lg * 4 + r) * 64 + f * 16 + lc] = accd[f][r];
  __syncthreads();

  // ---- cross-wave reduce, normalize, bf16, write ctx [B][N][H*64] ----
  const int oi = tid >> 4;
  const int d0 = (tid & 15) * 4;
  float4 p0 = *(float4*)&part[(size_t)(0  + oi) * 64 + d0];
  float4 p1 = *(float4*)&part[(size_t)(16 + oi) * 64 + d0];
  float4 p2 = *(float4*)&part[(size_t)(32 + oi) * 64 + d0];
  float4 p3 = *(float4*)&part[(size_t)(48 + oi) * 64 + d0];
  float iv = invr[oi];
  float4 tot;
  tot.x = (p0.x + p1.x + p2.x + p3.x) * iv;
  tot.y = (p0.y + p1.y + p2.y + p3.y) * iv;
  tot.z = (p0.z + p1.z + p2.z + p3.z) * iv;
  tot.w = (p0.w + p1.w + p2.w + p3.w) * iv;
  ushort4 o;
  o.x = f2bf(tot.x); o.y = f2bf(tot.y); o.z = f2bf(tot.z); o.w = f2bf(tot.w);
  *(ushort4*)&ctx[(size_t)(b * NSEQ + i0 + oi) * DMODEL + h * HD + d0] = o;
}

extern "C" void kernel_launch(void* const* d_in, const int* in_sizes, int n_in,
                              void* d_out, int out_size, void* d_ws, size_t ws_size,
                              hipStream_t stream) {
  const float* src     = (const float*)d_in[0];
  const float* sin_src = (const float*)d_in[1];
  const float* cos_src = (const float*)d_in[2];
  const float* tgt     = (const float*)d_in[3];
  const float* sin_tgt = (const float*)d_in[4];
  const float* cos_tgt = (const float*)d_in[5];
  const float* wq      = (const float*)d_in[6];
  const float* wkv     = (const float*)d_in[7];
  const float* wout    = (const float*)d_in[8];
  const float* bout    = (const float*)d_in[9];

  if (ws_size < (size_t)109051904) return;  // need ~104 MB scratch

  uint8_t* w = (uint8_t*)d_ws;
  unsigned short* tgt_bf = (unsigned short*)(w + 0);
  unsigned short* src_bf = (unsigned short*)(w + 8388608);
  unsigned short* wq_t   = (unsigned short*)(w + 16777216);
  unsigned short* wkv_t  = (unsigned short*)(w + 18874368);
  unsigned short* wout_t = (unsigned short*)(w + 23068672);
  float*          q_ws   = (float*)(w + 25165824);
  float*          kv_ws  = (float*)(w + 41943040);
  unsigned short* qhb    = (unsigned short*)(w + 75497472);
  unsigned short* khb    = (unsigned short*)(w + 83886080);
  unsigned short* vtb    = (unsigned short*)(w + 92274688);
  unsigned short* ctx    = (unsigned short*)(w + 100663296);

  float* out_p  = (float*)d_out;
  float* attn_p = out_p + (size_t)NB * NSEQ * DMODEL;

  // bf16 conversions of activations + transposed bf16 weights
  k_convert<<<4096, 256, 0, stream>>>(tgt, tgt_bf, 1048576);
  k_convert<<<4096, 256, 0, stream>>>(src, src_bf, 1048576);
  k_transpose<<<dim3(16, 16), 256, 0, stream>>>(wq,   wq_t,   1024, 1024);
  k_transpose<<<dim3(32, 16), 256, 0, stream>>>(wkv,  wkv_t,  1024, 2048);
  k_transpose<<<dim3(16, 16), 256, 0, stream>>>(wout, wout_t, 1024, 1024);

  // projections
  k_gemm<<<dim3(8, 32),  256, 0, stream>>>(tgt_bf, wq_t,  q_ws,  nullptr, 4096, 1024, 1024);
  k_gemm<<<dim3(16, 32), 256, 0, stream>>>(src_bf, wkv_t, kv_ws, nullptr, 4096, 2048, 1024);

  // RoPE + relayouts
  k_rope<<<8192, 256, 0, stream>>>(q_ws, 1024, sin_tgt, cos_tgt, qhb);
  k_rope<<<8192, 256, 0, stream>>>(kv_ws, 2048, sin_src, cos_src, khb);
  k_vtrans<<<dim3(32, 16, 2), 256, 0, stream>>>(kv_ws, vtb);

  // fused attention (writes attn fp32 + ctx bf16)
  k_attn<<<dim3(128, 16, 2), 256, 0, stream>>>(qhb, khb, vtb, attn_p, ctx);

  // output projection + bias
  k_gemm<<<dim3(8, 32), 256, 0, stream>>>(ctx, wout_t, out_p, bout, 4096, 1024, 1024);
}

// Round 2
// 459.564 us; speedup vs baseline: 1.5611x; 1.5611x over previous
//
#include <hip/hip_runtime.h>
#include <hip/hip_bf16.h>
#include <cstdint>
#include <cstddef>

#define NB 2
#define NSEQ 2048
#define NHEADS 16
#define HD 64
#define DMODEL 1024
#define SCALEF 0.125f

typedef __attribute__((ext_vector_type(4))) float f32x4;
typedef __attribute__((ext_vector_type(8))) short s16x8;

__device__ __forceinline__ unsigned short f2bf(float f) {
  union { float f; unsigned u; } v; v.f = f;
  unsigned u = v.u;
  return (unsigned short)((u + 0x7fffu + ((u >> 16) & 1u)) >> 16);
}

// ---------- fp32 -> bf16 straight convert (float4 vectorized) ----------
__global__ void k_convert(const float* __restrict__ in, unsigned short* __restrict__ out, int n4) {
  int i = blockIdx.x * blockDim.x + threadIdx.x;
  if (i >= n4) return;
  float4 v = ((const float4*)in)[i];
  ushort4 o;
  o.x = f2bf(v.x); o.y = f2bf(v.y); o.z = f2bf(v.z); o.w = f2bf(v.w);
  ((ushort4*)out)[i] = o;
}

// ---------- w [K][N] fp32 -> wt [N][K] bf16 (LDS-tiled transpose) ----------
__global__ void k_transpose(const float* __restrict__ w, unsigned short* __restrict__ wt, int K, int N) {
  __shared__ float t[64][65];
  int n0 = blockIdx.x * 64, k0 = blockIdx.y * 64;
  int c = threadIdx.x & 63, rb = threadIdx.x >> 6;
#pragma unroll
  for (int rr = 0; rr < 16; rr++) {
    int k = rb * 16 + rr;
    t[c][k] = w[(size_t)(k0 + k) * N + n0 + c];
  }
  __syncthreads();
#pragma unroll
  for (int rr = 0; rr < 16; rr++) {
    int n = rb * 16 + rr;
    wt[(size_t)(n0 + n) * K + k0 + c] = f2bf(t[n][c]);
  }
}

// ---------- bf16 MFMA GEMM: C[M][N] = A[M][K] @ Bt[N][K]^T (+bias) ----------
#define GLD16(gp, lp) __builtin_amdgcn_global_load_lds( \
    (const __attribute__((address_space(1))) unsigned int*)(gp), \
    (__attribute__((address_space(3))) unsigned int*)(lp), 16, 0, 0)

__global__ __launch_bounds__(256) void k_gemm(const unsigned short* __restrict__ A,
                                              const unsigned short* __restrict__ Bt,
                                              float* __restrict__ C,
                                              const float* __restrict__ bias,
                                              int M, int N, int K) {
  __shared__ unsigned short As[128 * 32];
  __shared__ unsigned short Bs[128 * 32];
  const int tid = threadIdx.x;
  const int lane = tid & 63, wid = tid >> 6;
  const int m0 = blockIdx.y * 128, n0 = blockIdx.x * 128;
  const int wr = wid >> 1, wc = wid & 1;
  const int lr = lane >> 2, l4 = lane & 3;
  const int lc = lane & 15, lg = lane >> 4;

  const unsigned short* pa0 = A + (size_t)(m0 + wid * 32 + lr) * K + l4 * 8;
  const unsigned short* pa1 = pa0 + (size_t)16 * K;
  const unsigned short* pb0 = Bt + (size_t)(n0 + wid * 32 + lr) * K + l4 * 8;
  const unsigned short* pb1 = pb0 + (size_t)16 * K;

  f32x4 acc[4][4] = {};

  for (int kt = 0; kt < K; kt += 32) {
    GLD16(pa0 + kt, &As[wid * 1024]);
    GLD16(pa1 + kt, &As[wid * 1024 + 512]);
    GLD16(pb0 + kt, &Bs[wid * 1024]);
    GLD16(pb1 + kt, &Bs[wid * 1024 + 512]);
    __syncthreads();
    s16x8 af[4], bfr[4];
#pragma unroll
    for (int m = 0; m < 4; m++)
      af[m] = *(const s16x8*)&As[(wr * 64 + m * 16 + lc) * 32 + lg * 8];
#pragma unroll
    for (int n = 0; n < 4; n++)
      bfr[n] = *(const s16x8*)&Bs[(wc * 64 + n * 16 + lc) * 32 + lg * 8];
    __builtin_amdgcn_s_setprio(1);
#pragma unroll
    for (int m = 0; m < 4; m++)
#pragma unroll
      for (int n = 0; n < 4; n++)
        acc[m][n] = __builtin_amdgcn_mfma_f32_16x16x32_bf16(af[m], bfr[n], acc[m][n], 0, 0, 0);
    __builtin_amdgcn_s_setprio(0);
    __syncthreads();
  }

  float bv[4] = {0.f, 0.f, 0.f, 0.f};
  if (bias) {
#pragma unroll
    for (int n = 0; n < 4; n++) bv[n] = bias[n0 + wc * 64 + n * 16 + lc];
  }
#pragma unroll
  for (int m = 0; m < 4; m++) {
#pragma unroll
    for (int n = 0; n < 4; n++) {
      int col = n0 + wc * 64 + n * 16 + lc;
#pragma unroll
      for (int r = 0; r < 4; r++) {
        int row = m0 + wr * 64 + m * 16 + lg * 4 + r;
        C[(size_t)row * N + col] = acc[m][n][r] + bv[n];
      }
    }
  }
}

// ---------- RoPE + head-split relayout: [B][N][H*64] f32 -> [B][H][N][64] bf16 ----------
__global__ void k_rope(const float* __restrict__ src, int row_stride,
                       const float* __restrict__ sinp, const float* __restrict__ cosp,
                       unsigned short* __restrict__ dst) {
  int tid = blockIdx.x * 256 + threadIdx.x;
  int p = tid & 31;
  int h = (tid >> 5) & 15;
  int i = (tid >> 9) & 2047;
  int b = tid >> 20;
  int d = p * 2;
  float2 x = *(const float2*)(src + (size_t)(b * NSEQ + i) * row_stride + h * HD + d);
  float o0, o1;
  if (p < 16) {
    size_t sc = (size_t)(b * NSEQ + i) * 32 + d;
    float2 cc = *(const float2*)(cosp + sc);
    float2 ss = *(const float2*)(sinp + sc);
    o0 = x.x * cc.x - x.y * ss.x;
    o1 = x.y * cc.y + x.x * ss.y;
  } else { o0 = x.x; o1 = x.y; }
  size_t off = ((size_t)(b * NHEADS + h) * NSEQ + i) * HD + d;
  unsigned pack = (unsigned)f2bf(o0) | ((unsigned)f2bf(o1) << 16);
  *(unsigned*)(dst + off) = pack;
}

// ---------- v relayout+transpose: kv[B][N][2048](cols 1024..) -> vt [B][H][64][N] bf16 ----------
__global__ void k_vtrans(const float* __restrict__ kv, unsigned short* __restrict__ vt) {
  __shared__ float t[64][65];
  int i0 = blockIdx.x * 64;
  int h = blockIdx.y, b = blockIdx.z;
  int c = threadIdx.x & 63, rb = threadIdx.x >> 6;
#pragma unroll
  for (int rr = 0; rr < 16; rr++) {
    int il = rb * 16 + rr;
    t[il][c] = kv[(size_t)(b * NSEQ + i0 + il) * 2048 + 1024 + h * HD + c];
  }
  __syncthreads();
#pragma unroll
  for (int rr = 0; rr < 16; rr++) {
    int dd = rb * 16 + rr;
    vt[((size_t)(b * NHEADS + h) * HD + dd) * NSEQ + i0 + c] = f2bf(t[c][dd]);
  }
}

// ---------- fused attention v2: 512 thr (8 waves), 16 q-rows ----------
// QK^T(+online max) -> bar -> max combine -> bar -> exp in regs (write e to S,
// write e*inv nontemporal to global attn) -> bar -> PV -> staged reduce -> ctx
__global__ __launch_bounds__(512) void k_attn(const unsigned short* __restrict__ qh,
                                              const unsigned short* __restrict__ kh,
                                              const unsigned short* __restrict__ vt,
                                              float* __restrict__ attn_g,
                                              unsigned short* __restrict__ ctx) {
  const int SROW = NSEQ + 4;
  __shared__ float S[16 * (NSEQ + 4)];       // 131,328 B
  __shared__ float part[4][16][64];          // 16,384 B
  __shared__ float wmax[8][16];
  __shared__ float rowmax_s[16];
  __shared__ float invr[16];

  const int tid = threadIdx.x;
  const int lane = tid & 63, wid = tid >> 6;   // wid 0..7
  const int i0 = blockIdx.x * 16;
  const int h = blockIdx.y, b = blockIdx.z;
  const int lc = lane & 15, lg = lane >> 4;

  const unsigned short* qb = qh + ((size_t)(b * NHEADS + h) * NSEQ + i0) * HD;
  const unsigned short* kb = kh + (size_t)(b * NHEADS + h) * NSEQ * HD;
  const unsigned short* vb = vt + (size_t)(b * NHEADS + h) * HD * NSEQ;

  // ---- QK^T: each wave covers 256 cols = 16 tiles of 16; track row-max ----
  s16x8 aq0 = *(const s16x8*)&qb[lc * HD + lg * 8];
  s16x8 aq1 = *(const s16x8*)&qb[lc * HD + 32 + lg * 8];
  float mx[4] = {-1e30f, -1e30f, -1e30f, -1e30f};
#pragma unroll 4
  for (int jf = 0; jf < 16; jf++) {
    int j = wid * 256 + jf * 16;
    f32x4 acc = {};
    s16x8 bk0 = *(const s16x8*)&kb[(size_t)(j + lc) * HD + lg * 8];
    s16x8 bk1 = *(const s16x8*)&kb[(size_t)(j + lc) * HD + 32 + lg * 8];
    __builtin_amdgcn_s_setprio(1);
    acc = __builtin_amdgcn_mfma_f32_16x16x32_bf16(aq0, bk0, acc, 0, 0, 0);
    acc = __builtin_amdgcn_mfma_f32_16x16x32_bf16(aq1, bk1, acc, 0, 0, 0);
    __builtin_amdgcn_s_setprio(0);
#pragma unroll
    for (int r = 0; r < 4; r++) {
      float v = acc[r] * SCALEF;
      S[(size_t)(lg * 4 + r) * SROW + j + lc] = v;
      mx[r] = fmaxf(mx[r], v);
    }
  }
  // cross-lane max over the 16 lanes sharing lg (cols)
#pragma unroll
  for (int off = 1; off <= 8; off <<= 1)
#pragma unroll
    for (int r = 0; r < 4; r++) mx[r] = fmaxf(mx[r], __shfl_xor(mx[r], off));
  if (lc == 0) {
#pragma unroll
    for (int r = 0; r < 4; r++) wmax[wid][lg * 4 + r] = mx[r];
  }
  __syncthreads();
  if (tid < 16) {
    float m = -1e30f;
#pragma unroll
    for (int w = 0; w < 8; w++) m = fmaxf(m, wmax[w][tid]);
    rowmax_s[tid] = m;
  }
  __syncthreads();

  // ---- exp + sum (register-resident), write e to S, e*inv to global ----
  const int row = tid >> 5;          // 16 rows, 32 threads each
  const int c = tid & 31;            // thread's float4 column lane
  float m = rowmax_s[row];
  float* Srow = S + (size_t)row * SROW;
  f32x4 e[16];
  float sum = 0.f;
#pragma unroll
  for (int mi = 0; mi < 16; mi++) {
    f32x4 v = *(f32x4*)&Srow[c * 4 + mi * 128];
    v[0] = __expf(v[0] - m); v[1] = __expf(v[1] - m);
    v[2] = __expf(v[2] - m); v[3] = __expf(v[3] - m);
    e[mi] = v;
    *(f32x4*)&Srow[c * 4 + mi * 128] = v;     // unnormalized exp for PV
    sum += v[0] + v[1] + v[2] + v[3];
  }
#pragma unroll
  for (int off = 1; off <= 16; off <<= 1) sum += __shfl_xor(sum, off);
  float inv = 1.0f / sum;
  if (c == 0) invr[row] = inv;

  float* arow = attn_g + ((size_t)(b * NHEADS + h) * NSEQ + i0 + row) * NSEQ;
#pragma unroll
  for (int mi = 0; mi < 16; mi++) {
    f32x4 v = e[mi];
    v[0] *= inv; v[1] *= inv; v[2] *= inv; v[3] *= inv;
    __builtin_nontemporal_store(v, (f32x4*)&arow[c * 4 + mi * 128]);
  }
  __syncthreads();

  // ---- PV: each wave covers its 256-col slice = 8 tiles of 32 ----
  f32x4 accd[4] = {};
#pragma unroll 2
  for (int jj = 0; jj < 8; jj++) {
    int jb = wid * 256 + jj * 32;
    f32x4 a0 = *(f32x4*)&S[(size_t)lc * SROW + jb + lg * 8];
    f32x4 a1 = *(f32x4*)&S[(size_t)lc * SROW + jb + lg * 8 + 4];
    s16x8 af;
    af[0] = (short)f2bf(a0[0]); af[1] = (short)f2bf(a0[1]);
    af[2] = (short)f2bf(a0[2]); af[3] = (short)f2bf(a0[3]);
    af[4] = (short)f2bf(a1[0]); af[5] = (short)f2bf(a1[1]);
    af[6] = (short)f2bf(a1[2]); af[7] = (short)f2bf(a1[3]);
    __builtin_amdgcn_s_setprio(1);
#pragma unroll
    for (int f = 0; f < 4; f++) {
      s16x8 bv = *(const s16x8*)&vb[(size_t)(f * 16 + lc) * NSEQ + jb + lg * 8];
      accd[f] = __builtin_amdgcn_mfma_f32_16x16x32_bf16(af, bv, accd[f], 0, 0, 0);
    }
    __builtin_amdgcn_s_setprio(0);
  }
  // staged cross-wave reduce: waves 0-3 write, waves 4-7 accumulate
  if (wid < 4) {
#pragma unroll
    for (int f = 0; f < 4; f++)
#pragma unroll
      for (int r = 0; r < 4; r++)
        part[wid][lg * 4 + r][f * 16 + lc] = accd[f][r];
  }
  __syncthreads();
  if (wid >= 4) {
#pragma unroll
    for (int f = 0; f < 4; f++)
#pragma unroll
      for (int r = 0; r < 4; r++)
        part[wid - 4][lg * 4 + r][f * 16 + lc] += accd[f][r];
  }
  __syncthreads();

  // ---- final reduce, normalize, bf16, write ctx [B][N][H*64] ----
  if (tid < 256) {
    const int oi = tid >> 4;
    const int d0 = (tid & 15) * 4;
    float4 p0 = *(float4*)&part[0][oi][d0];
    float4 p1 = *(float4*)&part[1][oi][d0];
    float4 p2 = *(float4*)&part[2][oi][d0];
    float4 p3 = *(float4*)&part[3][oi][d0];
    float iv = invr[oi];
    float4 tot;
    tot.x = (p0.x + p1.x + p2.x + p3.x) * iv;
    tot.y = (p0.y + p1.y + p2.y + p3.y) * iv;
    tot.z = (p0.z + p1.z + p2.z + p3.z) * iv;
    tot.w = (p0.w + p1.w + p2.w + p3.w) * iv;
    ushort4 o;
    o.x = f2bf(tot.x); o.y = f2bf(tot.y); o.z = f2bf(tot.z); o.w = f2bf(tot.w);
    *(ushort4*)&ctx[(size_t)(b * NSEQ + i0 + oi) * DMODEL + h * HD + d0] = o;
  }
}

extern "C" void kernel_launch(void* const* d_in, const int* in_sizes, int n_in,
                              void* d_out, int out_size, void* d_ws, size_t ws_size,
                              hipStream_t stream) {
  const float* src     = (const float*)d_in[0];
  const float* sin_src = (const float*)d_in[1];
  const float* cos_src = (const float*)d_in[2];
  const float* tgt     = (const float*)d_in[3];
  const float* sin_tgt = (const float*)d_in[4];
  const float* cos_tgt = (const float*)d_in[5];
  const float* wq      = (const float*)d_in[6];
  const float* wkv     = (const float*)d_in[7];
  const float* wout    = (const float*)d_in[8];
  const float* bout    = (const float*)d_in[9];

  if (ws_size < (size_t)109051904) return;

  uint8_t* w = (uint8_t*)d_ws;
  unsigned short* tgt_bf = (unsigned short*)(w + 0);
  unsigned short* src_bf = (unsigned short*)(w + 8388608);
  unsigned short* wq_t   = (unsigned short*)(w + 16777216);
  unsigned short* wkv_t  = (unsigned short*)(w + 18874368);
  unsigned short* wout_t = (unsigned short*)(w + 23068672);
  float*          q_ws   = (float*)(w + 25165824);
  float*          kv_ws  = (float*)(w + 41943040);
  unsigned short* qhb    = (unsigned short*)(w + 75497472);
  unsigned short* khb    = (unsigned short*)(w + 83886080);
  unsigned short* vtb    = (unsigned short*)(w + 92274688);
  unsigned short* ctx    = (unsigned short*)(w + 100663296);

  float* out_p  = (float*)d_out;
  float* attn_p = out_p + (size_t)NB * NSEQ * DMODEL;

  k_convert<<<4096, 256, 0, stream>>>(tgt, tgt_bf, 1048576);
  k_convert<<<4096, 256, 0, stream>>>(src, src_bf, 1048576);
  k_transpose<<<dim3(16, 16), 256, 0, stream>>>(wq,   wq_t,   1024, 1024);
  k_transpose<<<dim3(32, 16), 256, 0, stream>>>(wkv,  wkv_t,  1024, 2048);
  k_transpose<<<dim3(16, 16), 256, 0, stream>>>(wout, wout_t, 1024, 1024);

  k_gemm<<<dim3(8, 32),  256, 0, stream>>>(tgt_bf, wq_t,  q_ws,  nullptr, 4096, 1024, 1024);
  k_gemm<<<dim3(16, 32), 256, 0, stream>>>(src_bf, wkv_t, kv_ws, nullptr, 4096, 2048, 1024);

  k_rope<<<8192, 256, 0, stream>>>(q_ws, 1024, sin_tgt, cos_tgt, qhb);
  k_rope<<<8192, 256, 0, stream>>>(kv_ws, 2048, sin_src, cos_src, khb);
  k_vtrans<<<dim3(32, 16, 2), 256, 0, stream>>>(kv_ws, vtb);

  k_attn<<<dim3(128, 16, 2), 512, 0, stream>>>(qhb, khb, vtb, attn_p, ctx);

  k_gemm<<<dim3(8, 32), 256, 0, stream>>>(ctx, wout_t, out_p, bout, 4096, 1024, 1024);
}

// Round 3
// 412.790 us; speedup vs baseline: 1.7380x; 1.1133x over previous
//
#include <hip/hip_runtime.h>
#include <hip/hip_bf16.h>
#include <cstdint>
#include <cstddef>

#define NB 2
#define NSEQ 2048
#define NHEADS 16
#define HD 64
#define DMODEL 1024
#define SCALEF 0.125f

typedef __attribute__((ext_vector_type(4))) float f32x4;
typedef __attribute__((ext_vector_type(8))) short s16x8;

__device__ __forceinline__ unsigned short f2bf(float f) {
  union { float f; unsigned u; } v; v.f = f;
  unsigned u = v.u;
  return (unsigned short)((u + 0x7fffu + ((u >> 16) & 1u)) >> 16);
}

// ---------- fp32 -> bf16 straight convert (float4 vectorized) ----------
__global__ void k_convert(const float* __restrict__ in, unsigned short* __restrict__ out, int n4) {
  int i = blockIdx.x * blockDim.x + threadIdx.x;
  if (i >= n4) return;
  float4 v = ((const float4*)in)[i];
  ushort4 o;
  o.x = f2bf(v.x); o.y = f2bf(v.y); o.z = f2bf(v.z); o.w = f2bf(v.w);
  ((ushort4*)out)[i] = o;
}

// ---------- w [K][N] fp32 -> wt [N][K] bf16 (LDS-tiled transpose) ----------
__global__ void k_transpose(const float* __restrict__ w, unsigned short* __restrict__ wt, int K, int N) {
  __shared__ float t[64][65];
  int n0 = blockIdx.x * 64, k0 = blockIdx.y * 64;
  int c = threadIdx.x & 63, rb = threadIdx.x >> 6;
#pragma unroll
  for (int rr = 0; rr < 16; rr++) {
    int k = rb * 16 + rr;
    t[c][k] = w[(size_t)(k0 + k) * N + n0 + c];
  }
  __syncthreads();
#pragma unroll
  for (int rr = 0; rr < 16; rr++) {
    int n = rb * 16 + rr;
    wt[(size_t)(n0 + n) * K + k0 + c] = f2bf(t[n][c]);
  }
}

// ---------- bf16 MFMA GEMM: C[M][N] = A[M][K] @ Bt[N][K]^T (+bias) ----------
#define GLD16(gp, lp) __builtin_amdgcn_global_load_lds( \
    (const __attribute__((address_space(1))) unsigned int*)(gp), \
    (__attribute__((address_space(3))) unsigned int*)(lp), 16, 0, 0)

__global__ __launch_bounds__(256) void k_gemm(const unsigned short* __restrict__ A,
                                              const unsigned short* __restrict__ Bt,
                                              float* __restrict__ C,
                                              const float* __restrict__ bias,
                                              int M, int N, int K) {
  __shared__ unsigned short As[128 * 32];
  __shared__ unsigned short Bs[128 * 32];
  const int tid = threadIdx.x;
  const int lane = tid & 63, wid = tid >> 6;
  const int m0 = blockIdx.y * 128, n0 = blockIdx.x * 128;
  const int wr = wid >> 1, wc = wid & 1;
  const int lr = lane >> 2, l4 = lane & 3;
  const int lc = lane & 15, lg = lane >> 4;

  const unsigned short* pa0 = A + (size_t)(m0 + wid * 32 + lr) * K + l4 * 8;
  const unsigned short* pa1 = pa0 + (size_t)16 * K;
  const unsigned short* pb0 = Bt + (size_t)(n0 + wid * 32 + lr) * K + l4 * 8;
  const unsigned short* pb1 = pb0 + (size_t)16 * K;

  f32x4 acc[4][4] = {};

  for (int kt = 0; kt < K; kt += 32) {
    GLD16(pa0 + kt, &As[wid * 1024]);
    GLD16(pa1 + kt, &As[wid * 1024 + 512]);
    GLD16(pb0 + kt, &Bs[wid * 1024]);
    GLD16(pb1 + kt, &Bs[wid * 1024 + 512]);
    __syncthreads();
    s16x8 af[4], bfr[4];
#pragma unroll
    for (int m = 0; m < 4; m++)
      af[m] = *(const s16x8*)&As[(wr * 64 + m * 16 + lc) * 32 + lg * 8];
#pragma unroll
    for (int n = 0; n < 4; n++)
      bfr[n] = *(const s16x8*)&Bs[(wc * 64 + n * 16 + lc) * 32 + lg * 8];
    __builtin_amdgcn_s_setprio(1);
#pragma unroll
    for (int m = 0; m < 4; m++)
#pragma unroll
      for (int n = 0; n < 4; n++)
        acc[m][n] = __builtin_amdgcn_mfma_f32_16x16x32_bf16(af[m], bfr[n], acc[m][n], 0, 0, 0);
    __builtin_amdgcn_s_setprio(0);
    __syncthreads();
  }

  float bv[4] = {0.f, 0.f, 0.f, 0.f};
  if (bias) {
#pragma unroll
    for (int n = 0; n < 4; n++) bv[n] = bias[n0 + wc * 64 + n * 16 + lc];
  }
#pragma unroll
  for (int m = 0; m < 4; m++) {
#pragma unroll
    for (int n = 0; n < 4; n++) {
      int col = n0 + wc * 64 + n * 16 + lc;
#pragma unroll
      for (int r = 0; r < 4; r++) {
        int row = m0 + wr * 64 + m * 16 + lg * 4 + r;
        C[(size_t)row * N + col] = acc[m][n][r] + bv[n];
      }
    }
  }
}

// ---------- RoPE + head-split relayout: [B][N][H*64] f32 -> [B][H][N][64] bf16 ----------
__global__ void k_rope(const float* __restrict__ src, int row_stride,
                       const float* __restrict__ sinp, const float* __restrict__ cosp,
                       unsigned short* __restrict__ dst) {
  int tid = blockIdx.x * 256 + threadIdx.x;
  int p = tid & 31;
  int h = (tid >> 5) & 15;
  int i = (tid >> 9) & 2047;
  int b = tid >> 20;
  int d = p * 2;
  float2 x = *(const float2*)(src + (size_t)(b * NSEQ + i) * row_stride + h * HD + d);
  float o0, o1;
  if (p < 16) {
    size_t sc = (size_t)(b * NSEQ + i) * 32 + d;
    float2 cc = *(const float2*)(cosp + sc);
    float2 ss = *(const float2*)(sinp + sc);
    o0 = x.x * cc.x - x.y * ss.x;
    o1 = x.y * cc.y + x.x * ss.y;
  } else { o0 = x.x; o1 = x.y; }
  size_t off = ((size_t)(b * NHEADS + h) * NSEQ + i) * HD + d;
  unsigned pack = (unsigned)f2bf(o0) | ((unsigned)f2bf(o1) << 16);
  *(unsigned*)(dst + off) = pack;
}

// ---------- v relayout+transpose: kv[B][N][2048](cols 1024..) -> vt [B][H][64][N] bf16 ----------
__global__ void k_vtrans(const float* __restrict__ kv, unsigned short* __restrict__ vt) {
  __shared__ float t[64][65];
  int i0 = blockIdx.x * 64;
  int h = blockIdx.y, b = blockIdx.z;
  int c = threadIdx.x & 63, rb = threadIdx.x >> 6;
#pragma unroll
  for (int rr = 0; rr < 16; rr++) {
    int il = rb * 16 + rr;
    t[il][c] = kv[(size_t)(b * NSEQ + i0 + il) * 2048 + 1024 + h * HD + c];
  }
  __syncthreads();
#pragma unroll
  for (int rr = 0; rr < 16; rr++) {
    int dd = rb * 16 + rr;
    vt[((size_t)(b * NHEADS + h) * HD + dd) * NSEQ + i0 + c] = f2bf(t[c][dd]);
  }
}

// ---------- fused attention v3: scores in registers, bf16 LDS, 2 blocks/CU ----------
// 512 thr (8 waves), 16 q-rows. Each wave owns a 16x256 score chunk in VGPRs.
// QK^T(regs) -> max combine -> exp in regs (bf16 e -> LDS) -> sum combine ->
// normalized fp32 attn -> global (nontemporal) -> PV (bf16 LDS) -> reduce -> ctx
#define SROWB 2056
__global__ __launch_bounds__(512, 4) void k_attn(const unsigned short* __restrict__ qh,
                                                 const unsigned short* __restrict__ kh,
                                                 const unsigned short* __restrict__ vt,
                                                 float* __restrict__ attn_g,
                                                 unsigned short* __restrict__ ctx) {
  __shared__ unsigned short Sbf[16 * SROWB];   // 65,792 B (bf16 e-values)
  __shared__ float wred[8][16];                // per-wave max, then per-wave sum
  __shared__ float rowmax_s[16];
  __shared__ float invr[16];
  float* part = (float*)Sbf;                   // aliased after PV: [4][16][64]

  const int tid = threadIdx.x;
  const int lane = tid & 63, wid = tid >> 6;   // wid 0..7
  const int i0 = blockIdx.x * 16;
  const int h = blockIdx.y, b = blockIdx.z;
  const int lc = lane & 15, lg = lane >> 4;

  const unsigned short* qb = qh + ((size_t)(b * NHEADS + h) * NSEQ + i0) * HD;
  const unsigned short* kb = kh + (size_t)(b * NHEADS + h) * NSEQ * HD;
  const unsigned short* vb = vt + (size_t)(b * NHEADS + h) * HD * NSEQ;

  // ---- QK^T: wave covers cols [wid*256, wid*256+256); scores stay in regs ----
  s16x8 aq0 = *(const s16x8*)&qb[lc * HD + lg * 8];
  s16x8 aq1 = *(const s16x8*)&qb[lc * HD + 32 + lg * 8];
  f32x4 sc[16];
  float mx[4] = {-1e30f, -1e30f, -1e30f, -1e30f};
#pragma unroll
  for (int jf = 0; jf < 16; jf++) {
    int j = wid * 256 + jf * 16;
    f32x4 acc = {};
    s16x8 bk0 = *(const s16x8*)&kb[(size_t)(j + lc) * HD + lg * 8];
    s16x8 bk1 = *(const s16x8*)&kb[(size_t)(j + lc) * HD + 32 + lg * 8];
    acc = __builtin_amdgcn_mfma_f32_16x16x32_bf16(aq0, bk0, acc, 0, 0, 0);
    acc = __builtin_amdgcn_mfma_f32_16x16x32_bf16(aq1, bk1, acc, 0, 0, 0);
#pragma unroll
    for (int r = 0; r < 4; r++) {
      float v = acc[r] * SCALEF;
      sc[jf][r] = v;
      mx[r] = fmaxf(mx[r], v);
    }
  }
  // cross-lane max over the 16 lanes sharing lg
#pragma unroll
  for (int off = 1; off <= 8; off <<= 1)
#pragma unroll
    for (int r = 0; r < 4; r++) mx[r] = fmaxf(mx[r], __shfl_xor(mx[r], off));
  if (lc == 0) {
#pragma unroll
    for (int r = 0; r < 4; r++) wred[wid][lg * 4 + r] = mx[r];
  }
  __syncthreads();
  if (tid < 16) {
    float m = -1e30f;
#pragma unroll
    for (int w = 0; w < 8; w++) m = fmaxf(m, wred[w][tid]);
    rowmax_s[tid] = m;
  }
  __syncthreads();

  // ---- exp in regs; write unnormalized bf16 e to LDS; partial row sums ----
  float mrow[4], psum[4] = {0.f, 0.f, 0.f, 0.f};
#pragma unroll
  for (int r = 0; r < 4; r++) mrow[r] = rowmax_s[lg * 4 + r];
#pragma unroll
  for (int jf = 0; jf < 16; jf++) {
    int j = wid * 256 + jf * 16;
#pragma unroll
    for (int r = 0; r < 4; r++) {
      float e = __expf(sc[jf][r] - mrow[r]);
      sc[jf][r] = e;
      psum[r] += e;
      Sbf[(size_t)(lg * 4 + r) * SROWB + j + lc] = f2bf(e);
    }
  }
#pragma unroll
  for (int off = 1; off <= 8; off <<= 1)
#pragma unroll
    for (int r = 0; r < 4; r++) psum[r] += __shfl_xor(psum[r], off);
  if (lc == 0) {
#pragma unroll
    for (int r = 0; r < 4; r++) wred[wid][lg * 4 + r] = psum[r];
  }
  __syncthreads();
  if (tid < 16) {
    float s = 0.f;
#pragma unroll
    for (int w = 0; w < 8; w++) s += wred[w][tid];
    invr[tid] = 1.0f / s;
  }
  __syncthreads();

  // ---- normalized fp32 attn -> global (fire-and-forget) ----
  float ivr[4];
#pragma unroll
  for (int r = 0; r < 4; r++) ivr[r] = invr[lg * 4 + r];
  {
    float* ab = attn_g + ((size_t)(b * NHEADS + h) * NSEQ + i0) * NSEQ + wid * 256 + lc;
#pragma unroll
    for (int jf = 0; jf < 16; jf++) {
#pragma unroll
      for (int r = 0; r < 4; r++)
        __builtin_nontemporal_store(sc[jf][r] * ivr[r],
                                    ab + (size_t)(lg * 4 + r) * NSEQ + jf * 16);
    }
  }

  // ---- PV on unnormalized bf16 e: wave covers its 256-col slice ----
  f32x4 accd[4] = {};
#pragma unroll 2
  for (int jj = 0; jj < 8; jj++) {
    int jb = wid * 256 + jj * 32;
    s16x8 af = *(const s16x8*)&Sbf[(size_t)lc * SROWB + jb + lg * 8];
    __builtin_amdgcn_s_setprio(1);
#pragma unroll
    for (int f = 0; f < 4; f++) {
      s16x8 bv = *(const s16x8*)&vb[(size_t)(f * 16 + lc) * NSEQ + jb + lg * 8];
      accd[f] = __builtin_amdgcn_mfma_f32_16x16x32_bf16(af, bv, accd[f], 0, 0, 0);
    }
    __builtin_amdgcn_s_setprio(0);
  }
  __syncthreads();   // all PV reads of Sbf complete; part may now alias it

  // staged cross-wave reduce: waves 0-3 write, waves 4-7 accumulate
  if (wid < 4) {
#pragma unroll
    for (int f = 0; f < 4; f++)
#pragma unroll
      for (int r = 0; r < 4; r++)
        part[((size_t)wid * 16 + lg * 4 + r) * 64 + f * 16 + lc] = accd[f][r];
  }
  __syncthreads();
  if (wid >= 4) {
#pragma unroll
    for (int f = 0; f < 4; f++)
#pragma unroll
      for (int r = 0; r < 4; r++)
        part[((size_t)(wid - 4) * 16 + lg * 4 + r) * 64 + f * 16 + lc] += accd[f][r];
  }
  __syncthreads();

  // ---- final reduce, normalize, bf16, write ctx [B][N][H*64] ----
  if (tid < 256) {
    const int oi = tid >> 4;
    const int d0 = (tid & 15) * 4;
    float4 p0 = *(float4*)&part[((size_t)0 * 16 + oi) * 64 + d0];
    float4 p1 = *(float4*)&part[((size_t)1 * 16 + oi) * 64 + d0];
    float4 p2 = *(float4*)&part[((size_t)2 * 16 + oi) * 64 + d0];
    float4 p3 = *(float4*)&part[((size_t)3 * 16 + oi) * 64 + d0];
    float iv = invr[oi];
    float4 tot;
    tot.x = (p0.x + p1.x + p2.x + p3.x) * iv;
    tot.y = (p0.y + p1.y + p2.y + p3.y) * iv;
    tot.z = (p0.z + p1.z + p2.z + p3.z) * iv;
    tot.w = (p0.w + p1.w + p2.w + p3.w) * iv;
    ushort4 o;
    o.x = f2bf(tot.x); o.y = f2bf(tot.y); o.z = f2bf(tot.z); o.w = f2bf(tot.w);
    *(ushort4*)&ctx[(size_t)(b * NSEQ + i0 + oi) * DMODEL + h * HD + d0] = o;
  }
}

extern "C" void kernel_launch(void* const* d_in, const int* in_sizes, int n_in,
                              void* d_out, int out_size, void* d_ws, size_t ws_size,
                              hipStream_t stream) {
  const float* src     = (const float*)d_in[0];
  const float* sin_src = (const float*)d_in[1];
  const float* cos_src = (const float*)d_in[2];
  const float* tgt     = (const float*)d_in[3];
  const float* sin_tgt = (const float*)d_in[4];
  const float* cos_tgt = (const float*)d_in[5];
  const float* wq      = (const float*)d_in[6];
  const float* wkv     = (const float*)d_in[7];
  const float* wout    = (const float*)d_in[8];
  const float* bout    = (const float*)d_in[9];

  if (ws_size < (size_t)109051904) return;

  uint8_t* w = (uint8_t*)d_ws;
  unsigned short* tgt_bf = (unsigned short*)(w + 0);
  unsigned short* src_bf = (unsigned short*)(w + 8388608);
  unsigned short* wq_t   = (unsigned short*)(w + 16777216);
  unsigned short* wkv_t  = (unsigned short*)(w + 18874368);
  unsigned short* wout_t = (unsigned short*)(w + 23068672);
  float*          q_ws   = (float*)(w + 25165824);
  float*          kv_ws  = (float*)(w + 41943040);
  unsigned short* qhb    = (unsigned short*)(w + 75497472);
  unsigned short* khb    = (unsigned short*)(w + 83886080);
  unsigned short* vtb    = (unsigned short*)(w + 92274688);
  unsigned short* ctx    = (unsigned short*)(w + 100663296);

  float* out_p  = (float*)d_out;
  float* attn_p = out_p + (size_t)NB * NSEQ * DMODEL;

  k_convert<<<4096, 256, 0, stream>>>(tgt, tgt_bf, 1048576);
  k_convert<<<4096, 256, 0, stream>>>(src, src_bf, 1048576);
  k_transpose<<<dim3(16, 16), 256, 0, stream>>>(wq,   wq_t,   1024, 1024);
  k_transpose<<<dim3(32, 16), 256, 0, stream>>>(wkv,  wkv_t,  1024, 2048);
  k_transpose<<<dim3(16, 16), 256, 0, stream>>>(wout, wout_t, 1024, 1024);

  k_gemm<<<dim3(8, 32),  256, 0, stream>>>(tgt_bf, wq_t,  q_ws,  nullptr, 4096, 1024, 1024);
  k_gemm<<<dim3(16, 32), 256, 0, stream>>>(src_bf, wkv_t, kv_ws, nullptr, 4096, 2048, 1024);

  k_rope<<<8192, 256, 0, stream>>>(q_ws, 1024, sin_tgt, cos_tgt, qhb);
  k_rope<<<8192, 256, 0, stream>>>(kv_ws, 2048, sin_src, cos_src, khb);
  k_vtrans<<<dim3(32, 16, 2), 256, 0, stream>>>(kv_ws, vtb);

  k_attn<<<dim3(128, 16, 2), 512, 0, stream>>>(qhb, khb, vtb, attn_p, ctx);

  k_gemm<<<dim3(8, 32), 256, 0, stream>>>(ctx, wout_t, out_p, bout, 4096, 1024, 1024);
}